// Round 8
// baseline (222.905 us; speedup 1.0000x reference)
//
#include <hip/hip_runtime.h>
#include <math.h>

#define D     172
#define D4    43            // float4s per row
#define G3    516           // 3*D rows per weight matrix
#define RPB   8             // batch rows per GRU block
#define TPB   256
#define NCOPY 2048
#define WT_HALF (43 * 516)          // float4s per transposed matrix = 22188
#define WT_F4   (2 * WT_HALF)       // 44376

typedef float vfloat4 __attribute__((ext_vector_type(4)));

// ---------------------------------------------------------------------------
// Prologue: transpose weights into ws as Wt[m][k4][row] (float4 over k) so
// GRU weight loads are coalesced across lanes (lane d -> consecutive f4).
// ---------------------------------------------------------------------------
__global__ __launch_bounds__(256) void prep_kernel(const float* __restrict__ w_ih,
                                                   const float* __restrict__ w_hh,
                                                   float4* __restrict__ wt) {
    int idx = blockIdx.x * 256 + threadIdx.x;
    if (idx < WT_F4) {
        int m   = idx / WT_HALF;
        int rem = idx - m * WT_HALF;
        int k4  = rem / G3;
        int row = rem - k4 * G3;
        const float* src = m ? w_hh : w_ih;
        wt[idx] = *(const float4*)(src + (long)row * D + 4 * k4);
    }
}

// ---------------------------------------------------------------------------
// Copy kernel: memory -> out, last_update -> out tail. Lean (no LDS, few
// VGPRs). Main loop: 4 independent loads issued BEFORE any store, unguarded
// (trip-count-exact), so waits are progressive vmcnt(3..) instead of the
// load->vmcnt(0)->store chain that also drains store acks (R6's 2.9 TB/s
// failure mode). Guarded simple tail.
// ---------------------------------------------------------------------------
__global__ __launch_bounds__(TPB) void copy_kernel(const vfloat4* __restrict__ src,
                                                   vfloat4* __restrict__ dst,
                                                   const vfloat4* __restrict__ lu4,
                                                   vfloat4* __restrict__ outlu4,
                                                   unsigned nf4, unsigned luf4) {
    const unsigned tid = blockIdx.x * TPB + threadIdx.x;
    const unsigned S   = NCOPY * TPB;            // 524288 threads total

    unsigned i = tid;
    for (; i + 3u * S < nf4; i += 4u * S) {
        vfloat4 a = src[i];
        vfloat4 b = src[i + S];
        vfloat4 c = src[i + 2u * S];
        vfloat4 d = src[i + 3u * S];
        dst[i]          = a;
        dst[i + S]      = b;
        dst[i + 2u * S] = c;
        dst[i + 3u * S] = d;
    }
    for (; i < nf4; i += S) dst[i] = src[i];
    for (unsigned e = tid; e < luf4; e += S) outlu4[e] = lu4[e];
}

// ---------------------------------------------------------------------------
// GRU kernel (runs AFTER the bulk copy): computes 8 batch rows per block and
// scatters winner rows + timestamps directly into the output. Dup
// suppression: shared-memory flag any thread may set (benign OR-race);
// NOTE: __ballot is per-wave (64 lanes) on CDNA — never use it for a
// 256-thread block reduction (R5's bug).
// ---------------------------------------------------------------------------
__global__ __launch_bounds__(TPB) void gru_kernel(
    const int*   __restrict__ ids,  const float* __restrict__ msg,
    const float* __restrict__ ts,   const float* __restrict__ mem,
    const float* __restrict__ b_ih, const float* __restrict__ b_hh,
    const float4* __restrict__ wt,
    float* __restrict__ out_mem,    float* __restrict__ out_lu,
    int B) {

    __shared__ float4 sxh[2][RPB][D4];   // [0]=x (messages), [1]=h (gathered memory)
    __shared__ int    s_id[RPB];
    __shared__ int    s_dup[RPB];

    const int tid  = threadIdx.x;
    const int base = blockIdx.x * RPB;

    if (tid < RPB) {
        s_id[tid]  = ids[base + tid];
        s_dup[tid] = 0;
    }
    __syncthreads();

    for (int it = tid; it < 2 * RPB * D4; it += TPB) {
        int which = it / (RPB * D4);
        int rem   = it - which * (RPB * D4);
        int r     = rem / D4;
        int k4    = rem - r * D4;
        const float* src = which ? (mem + (long)s_id[r] * D)
                                 : (msg + (long)(base + r) * D);
        ((float4*)sxh)[it] = *(const float4*)(src + 4 * k4);
    }
    // duplicate scan: row r loses if any later batch index has the same id
    for (int r = 0; r < RPB; ++r) {
        int my = s_id[r];
        for (int j = base + r + 1 + tid; j < B; j += TPB) {
            if (ids[j] == my) { s_dup[r] = 1; break; }
        }
    }
    __syncthreads();

    if (tid < D) {
        float acc[6][RPB];
        #pragma unroll
        for (int g = 0; g < 6; ++g)
            #pragma unroll
            for (int r = 0; r < RPB; ++r) acc[g][r] = 0.0f;

        const float4* wtB = wt + WT_HALF;
        for (int k4 = 0; k4 < D4; ++k4) {
            const int o = k4 * G3 + tid;
            float4 a0 = wt [o];
            float4 a1 = wt [o + D];
            float4 a2 = wt [o + 2 * D];
            float4 c0 = wtB[o];
            float4 c1 = wtB[o + D];
            float4 c2 = wtB[o + 2 * D];
            #pragma unroll
            for (int r = 0; r < RPB; ++r) {
                float4 xv = sxh[0][r][k4];
                float4 hv = sxh[1][r][k4];
                acc[0][r] += a0.x * xv.x + a0.y * xv.y + a0.z * xv.z + a0.w * xv.w;
                acc[1][r] += a1.x * xv.x + a1.y * xv.y + a1.z * xv.z + a1.w * xv.w;
                acc[2][r] += a2.x * xv.x + a2.y * xv.y + a2.z * xv.z + a2.w * xv.w;
                acc[3][r] += c0.x * hv.x + c0.y * hv.y + c0.z * hv.z + c0.w * hv.w;
                acc[4][r] += c1.x * hv.x + c1.y * hv.y + c1.z * hv.z + c1.w * hv.w;
                acc[5][r] += c2.x * hv.x + c2.y * hv.y + c2.z * hv.z + c2.w * hv.w;
            }
        }

        float bir = b_ih[tid], biz = b_ih[D + tid], bin_ = b_ih[2 * D + tid];
        float bhr = b_hh[tid], bhz = b_hh[D + tid], bhn  = b_hh[2 * D + tid];
        #pragma unroll
        for (int r = 0; r < RPB; ++r) {
            float i_r = acc[0][r] + bir;
            float i_z = acc[1][r] + biz;
            float i_n = acc[2][r] + bin_;
            float h_r = acc[3][r] + bhr;
            float h_z = acc[4][r] + bhz;
            float h_n = acc[5][r] + bhn;
            float rg = 1.0f / (1.0f + expf(-(i_r + h_r)));
            float zg = 1.0f / (1.0f + expf(-(i_z + h_z)));
            float ng = tanhf(i_n + rg * h_n);
            float hv = ((const float*)sxh[1][r])[tid];
            float outv = (1.0f - zg) * ng + zg * hv;
            if (!s_dup[r]) out_mem[(long)s_id[r] * D + tid] = outv;
        }
    }
    if (tid < RPB && !s_dup[tid]) out_lu[s_id[tid]] = ts[base + tid];
}

// ---------------- fallback GRU (uncoalesced weights, if ws too small) ------
__global__ __launch_bounds__(TPB) void gru_direct_kernel(
    const int*   __restrict__ ids,  const float* __restrict__ msg,
    const float* __restrict__ ts,   const float* __restrict__ mem,
    const float* __restrict__ w_ih, const float* __restrict__ w_hh,
    const float* __restrict__ b_ih, const float* __restrict__ b_hh,
    float* __restrict__ out_mem,    float* __restrict__ out_lu, int B) {
    int r = blockIdx.x;
    int tid = threadIdx.x;
    __shared__ float sx[D], sh[D];
    __shared__ int s_id, s_dup;
    if (tid == 0) { s_id = ids[r]; s_dup = 0; }
    __syncthreads();
    if (tid < D) { sx[tid] = msg[(long)r * D + tid]; sh[tid] = mem[(long)s_id * D + tid]; }
    for (int j = r + 1 + tid; j < B; j += TPB) if (ids[j] == s_id) { s_dup = 1; break; }
    __syncthreads();
    if (s_dup) return;
    if (tid < D) {
        float a[6] = {0,0,0,0,0,0};
        for (int k = 0; k < D; ++k) {
            float xv = sx[k], hv = sh[k];
            a[0] += w_ih[(long)(0*D+tid)*D+k] * xv;
            a[1] += w_ih[(long)(1*D+tid)*D+k] * xv;
            a[2] += w_ih[(long)(2*D+tid)*D+k] * xv;
            a[3] += w_hh[(long)(0*D+tid)*D+k] * hv;
            a[4] += w_hh[(long)(1*D+tid)*D+k] * hv;
            a[5] += w_hh[(long)(2*D+tid)*D+k] * hv;
        }
        float rg = 1.0f / (1.0f + expf(-(a[0] + b_ih[tid] + a[3] + b_hh[tid])));
        float zg = 1.0f / (1.0f + expf(-(a[1] + b_ih[D+tid] + a[4] + b_hh[D+tid])));
        float ng = tanhf(a[2] + b_ih[2*D+tid] + rg * (a[5] + b_hh[2*D+tid]));
        out_mem[(long)s_id * D + tid] = (1.0f - zg) * ng + zg * sh[tid];
    }
    if (tid == 0) out_lu[s_id] = ts[r];
}

extern "C" void kernel_launch(void* const* d_in, const int* in_sizes, int n_in,
                              void* d_out, int out_size, void* d_ws, size_t ws_size,
                              hipStream_t stream) {
    const int*   node_ids    = (const int*)d_in[0];
    const float* messages    = (const float*)d_in[1];
    const float* timestamps  = (const float*)d_in[2];
    const float* memory      = (const float*)d_in[3];
    const float* last_update = (const float*)d_in[4];
    const float* w_ih        = (const float*)d_in[5];
    const float* w_hh        = (const float*)d_in[6];
    const float* b_ih        = (const float*)d_in[7];
    const float* b_hh        = (const float*)d_in[8];
    float* out = (float*)d_out;

    const int B = in_sizes[0];          // 4096
    const int N = in_sizes[4];          // 500000
    const long memf = (long)N * D;      // 86,000,000 floats

    copy_kernel<<<NCOPY, TPB, 0, stream>>>((const vfloat4*)memory,
                                           (vfloat4*)out,
                                           (const vfloat4*)last_update,
                                           (vfloat4*)(out + memf),
                                           (unsigned)(memf / 4), (unsigned)(N / 4));

    const size_t wt_bytes = (size_t)WT_F4 * sizeof(float4);
    if (ws_size >= wt_bytes) {
        float4* wt = (float4*)d_ws;
        prep_kernel<<<(WT_F4 + 255) / 256, 256, 0, stream>>>(w_ih, w_hh, wt);
        gru_kernel<<<B / RPB, TPB, 0, stream>>>(node_ids, messages, timestamps, memory,
                                                b_ih, b_hh, (const float4*)wt,
                                                out, out + memf, B);
    } else {
        gru_direct_kernel<<<B, TPB, 0, stream>>>(node_ids, messages, timestamps, memory,
                                                 w_ih, w_hh, b_ih, b_hh,
                                                 out, out + memf, B);
    }
}

// Round 9
// 215.276 us; speedup vs baseline: 1.0354x; 1.0354x over previous
//
#include <hip/hip_runtime.h>
#include <math.h>

#define D     172
#define D4    43            // float4s per row
#define G3    516           // 3*D rows per weight matrix
#define RPB   8             // batch rows per GRU block
#define TPB   256
#define NCOPY 2048
#define WT_HALF (43 * 516)          // float4s per transposed matrix = 22188
#define WT_F4   (2 * WT_HALF)       // 44376

typedef float vfloat4 __attribute__((ext_vector_type(4)));

// ---------------------------------------------------------------------------
// Prologue: transpose weights into ws as Wt[m][k4][row] (float4 over k) so
// GRU weight loads are coalesced across lanes (lane d -> consecutive f4).
// ---------------------------------------------------------------------------
__global__ __launch_bounds__(256) void prep_kernel(const float* __restrict__ w_ih,
                                                   const float* __restrict__ w_hh,
                                                   float4* __restrict__ wt) {
    int idx = blockIdx.x * 256 + threadIdx.x;
    if (idx < WT_F4) {
        int m   = idx / WT_HALF;
        int rem = idx - m * WT_HALF;
        int k4  = rem / G3;
        int row = rem - k4 * G3;
        const float* src = m ? w_hh : w_ih;
        wt[idx] = *(const float4*)(src + (long)row * D + 4 * k4);
    }
}

// ---------------------------------------------------------------------------
// Copy kernel: memory -> out, last_update -> out tail.
// ONE change vs R8: NONTEMPORAL stores. The write stream (344 MB) no longer
// allocates in L2/L3, so it stops thrashing the read stream's L3 residency
// (R6 showed ~50% of reads already L3-absorbed WITH the thrash). Loads stay
// cached on purpose — src can stay L3-resident across graph replays.
// ---------------------------------------------------------------------------
__global__ __launch_bounds__(TPB) void copy_kernel(const vfloat4* __restrict__ src,
                                                   vfloat4* __restrict__ dst,
                                                   const vfloat4* __restrict__ lu4,
                                                   vfloat4* __restrict__ outlu4,
                                                   unsigned nf4, unsigned luf4) {
    const unsigned tid = blockIdx.x * TPB + threadIdx.x;
    const unsigned S   = NCOPY * TPB;            // 524288 threads total

    unsigned i = tid;
    for (; i + 3u * S < nf4; i += 4u * S) {
        vfloat4 a = src[i];
        vfloat4 b = src[i + S];
        vfloat4 c = src[i + 2u * S];
        vfloat4 d = src[i + 3u * S];
        __builtin_nontemporal_store(a, &dst[i]);
        __builtin_nontemporal_store(b, &dst[i + S]);
        __builtin_nontemporal_store(c, &dst[i + 2u * S]);
        __builtin_nontemporal_store(d, &dst[i + 3u * S]);
    }
    for (; i < nf4; i += S) __builtin_nontemporal_store(src[i], &dst[i]);
    for (unsigned e = tid; e < luf4; e += S)
        __builtin_nontemporal_store(lu4[e], &outlu4[e]);
}

// ---------------------------------------------------------------------------
// GRU kernel (runs AFTER the bulk copy): computes 8 batch rows per block and
// scatters winner rows + timestamps directly into the output. Dup
// suppression: shared-memory flag any thread may set (benign OR-race);
// NOTE: __ballot is per-wave (64 lanes) on CDNA — never use it for a
// 256-thread block reduction (R5's bug).
// ---------------------------------------------------------------------------
__global__ __launch_bounds__(TPB) void gru_kernel(
    const int*   __restrict__ ids,  const float* __restrict__ msg,
    const float* __restrict__ ts,   const float* __restrict__ mem,
    const float* __restrict__ b_ih, const float* __restrict__ b_hh,
    const float4* __restrict__ wt,
    float* __restrict__ out_mem,    float* __restrict__ out_lu,
    int B) {

    __shared__ float4 sxh[2][RPB][D4];   // [0]=x (messages), [1]=h (gathered memory)
    __shared__ int    s_id[RPB];
    __shared__ int    s_dup[RPB];

    const int tid  = threadIdx.x;
    const int base = blockIdx.x * RPB;

    if (tid < RPB) {
        s_id[tid]  = ids[base + tid];
        s_dup[tid] = 0;
    }
    __syncthreads();

    for (int it = tid; it < 2 * RPB * D4; it += TPB) {
        int which = it / (RPB * D4);
        int rem   = it - which * (RPB * D4);
        int r     = rem / D4;
        int k4    = rem - r * D4;
        const float* src = which ? (mem + (long)s_id[r] * D)
                                 : (msg + (long)(base + r) * D);
        ((float4*)sxh)[it] = *(const float4*)(src + 4 * k4);
    }
    // duplicate scan: row r loses if any later batch index has the same id
    for (int r = 0; r < RPB; ++r) {
        int my = s_id[r];
        for (int j = base + r + 1 + tid; j < B; j += TPB) {
            if (ids[j] == my) { s_dup[r] = 1; break; }
        }
    }
    __syncthreads();

    if (tid < D) {
        float acc[6][RPB];
        #pragma unroll
        for (int g = 0; g < 6; ++g)
            #pragma unroll
            for (int r = 0; r < RPB; ++r) acc[g][r] = 0.0f;

        const float4* wtB = wt + WT_HALF;
        for (int k4 = 0; k4 < D4; ++k4) {
            const int o = k4 * G3 + tid;
            float4 a0 = wt [o];
            float4 a1 = wt [o + D];
            float4 a2 = wt [o + 2 * D];
            float4 c0 = wtB[o];
            float4 c1 = wtB[o + D];
            float4 c2 = wtB[o + 2 * D];
            #pragma unroll
            for (int r = 0; r < RPB; ++r) {
                float4 xv = sxh[0][r][k4];
                float4 hv = sxh[1][r][k4];
                acc[0][r] += a0.x * xv.x + a0.y * xv.y + a0.z * xv.z + a0.w * xv.w;
                acc[1][r] += a1.x * xv.x + a1.y * xv.y + a1.z * xv.z + a1.w * xv.w;
                acc[2][r] += a2.x * xv.x + a2.y * xv.y + a2.z * xv.z + a2.w * xv.w;
                acc[3][r] += c0.x * hv.x + c0.y * hv.y + c0.z * hv.z + c0.w * hv.w;
                acc[4][r] += c1.x * hv.x + c1.y * hv.y + c1.z * hv.z + c1.w * hv.w;
                acc[5][r] += c2.x * hv.x + c2.y * hv.y + c2.z * hv.z + c2.w * hv.w;
            }
        }

        float bir = b_ih[tid], biz = b_ih[D + tid], bin_ = b_ih[2 * D + tid];
        float bhr = b_hh[tid], bhz = b_hh[D + tid], bhn  = b_hh[2 * D + tid];
        #pragma unroll
        for (int r = 0; r < RPB; ++r) {
            float i_r = acc[0][r] + bir;
            float i_z = acc[1][r] + biz;
            float i_n = acc[2][r] + bin_;
            float h_r = acc[3][r] + bhr;
            float h_z = acc[4][r] + bhz;
            float h_n = acc[5][r] + bhn;
            float rg = 1.0f / (1.0f + expf(-(i_r + h_r)));
            float zg = 1.0f / (1.0f + expf(-(i_z + h_z)));
            float ng = tanhf(i_n + rg * h_n);
            float hv = ((const float*)sxh[1][r])[tid];
            float outv = (1.0f - zg) * ng + zg * hv;
            if (!s_dup[r]) out_mem[(long)s_id[r] * D + tid] = outv;
        }
    }
    if (tid < RPB && !s_dup[tid]) out_lu[s_id[tid]] = ts[base + tid];
}

// ---------------- fallback GRU (uncoalesced weights, if ws too small) ------
__global__ __launch_bounds__(TPB) void gru_direct_kernel(
    const int*   __restrict__ ids,  const float* __restrict__ msg,
    const float* __restrict__ ts,   const float* __restrict__ mem,
    const float* __restrict__ w_ih, const float* __restrict__ w_hh,
    const float* __restrict__ b_ih, const float* __restrict__ b_hh,
    float* __restrict__ out_mem,    float* __restrict__ out_lu, int B) {
    int r = blockIdx.x;
    int tid = threadIdx.x;
    __shared__ float sx[D], sh[D];
    __shared__ int s_id, s_dup;
    if (tid == 0) { s_id = ids[r]; s_dup = 0; }
    __syncthreads();
    if (tid < D) { sx[tid] = msg[(long)r * D + tid]; sh[tid] = mem[(long)s_id * D + tid]; }
    for (int j = r + 1 + tid; j < B; j += TPB) if (ids[j] == s_id) { s_dup = 1; break; }
    __syncthreads();
    if (s_dup) return;
    if (tid < D) {
        float a[6] = {0,0,0,0,0,0};
        for (int k = 0; k < D; ++k) {
            float xv = sx[k], hv = sh[k];
            a[0] += w_ih[(long)(0*D+tid)*D+k] * xv;
            a[1] += w_ih[(long)(1*D+tid)*D+k] * xv;
            a[2] += w_ih[(long)(2*D+tid)*D+k] * xv;
            a[3] += w_hh[(long)(0*D+tid)*D+k] * hv;
            a[4] += w_hh[(long)(1*D+tid)*D+k] * hv;
            a[5] += w_hh[(long)(2*D+tid)*D+k] * hv;
        }
        float rg = 1.0f / (1.0f + expf(-(a[0] + b_ih[tid] + a[3] + b_hh[tid])));
        float zg = 1.0f / (1.0f + expf(-(a[1] + b_ih[D+tid] + a[4] + b_hh[D+tid])));
        float ng = tanhf(a[2] + b_ih[2*D+tid] + rg * (a[5] + b_hh[2*D+tid]));
        out_mem[(long)s_id * D + tid] = (1.0f - zg) * ng + zg * sh[tid];
    }
    if (tid == 0) out_lu[s_id] = ts[r];
}

extern "C" void kernel_launch(void* const* d_in, const int* in_sizes, int n_in,
                              void* d_out, int out_size, void* d_ws, size_t ws_size,
                              hipStream_t stream) {
    const int*   node_ids    = (const int*)d_in[0];
    const float* messages    = (const float*)d_in[1];
    const float* timestamps  = (const float*)d_in[2];
    const float* memory      = (const float*)d_in[3];
    const float* last_update = (const float*)d_in[4];
    const float* w_ih        = (const float*)d_in[5];
    const float* w_hh        = (const float*)d_in[6];
    const float* b_ih        = (const float*)d_in[7];
    const float* b_hh        = (const float*)d_in[8];
    float* out = (float*)d_out;

    const int B = in_sizes[0];          // 4096
    const int N = in_sizes[4];          // 500000
    const long memf = (long)N * D;      // 86,000,000 floats

    copy_kernel<<<NCOPY, TPB, 0, stream>>>((const vfloat4*)memory,
                                           (vfloat4*)out,
                                           (const vfloat4*)last_update,
                                           (vfloat4*)(out + memf),
                                           (unsigned)(memf / 4), (unsigned)(N / 4));

    const size_t wt_bytes = (size_t)WT_F4 * sizeof(float4);
    if (ws_size >= wt_bytes) {
        float4* wt = (float4*)d_ws;
        prep_kernel<<<(WT_F4 + 255) / 256, 256, 0, stream>>>(w_ih, w_hh, wt);
        gru_kernel<<<B / RPB, TPB, 0, stream>>>(node_ids, messages, timestamps, memory,
                                                b_ih, b_hh, (const float4*)wt,
                                                out, out + memf, B);
    } else {
        gru_direct_kernel<<<B, TPB, 0, stream>>>(node_ids, messages, timestamps, memory,
                                                 w_ih, w_hh, b_ih, b_hh,
                                                 out, out + memf, B);
    }
}

// Round 10
// 181.844 us; speedup vs baseline: 1.2258x; 1.1839x over previous
//
#include <hip/hip_runtime.h>
#include <math.h>

#define D     172
#define D4    43            // float4s per row
#define G3    516           // 3*D rows per weight matrix
#define RPB   8             // batch rows per GRU block
#define TPB   256
#define WT_HALF (43 * 516)          // float4s per transposed matrix = 22188
#define WT_F4   (2 * WT_HALF)       // 44376

typedef float vfloat4 __attribute__((ext_vector_type(4)));

// ---------------------------------------------------------------------------
// Prologue: transpose weights into ws as Wt[m][k4][row] (float4 over k) so
// GRU weight loads are coalesced across lanes (lane d -> consecutive f4).
// ---------------------------------------------------------------------------
__global__ __launch_bounds__(256) void prep_kernel(const float* __restrict__ w_ih,
                                                   const float* __restrict__ w_hh,
                                                   float4* __restrict__ wt) {
    int idx = blockIdx.x * 256 + threadIdx.x;
    if (idx < WT_F4) {
        int m   = idx / WT_HALF;
        int rem = idx - m * WT_HALF;
        int k4  = rem / G3;
        int row = rem - k4 * G3;
        const float* src = m ? w_hh : w_ih;
        wt[idx] = *(const float4*)(src + (long)row * D + 4 * k4);
    }
}

// ---------------------------------------------------------------------------
// Copy kernel — MONOLITHIC, one float4 per thread, no loop. This matches the
// structure of the 6.75 TB/s rocclr fill (huge grid, fire-and-forget threads)
// and removes the loop-carried waitcnt/burst-alternation that every looped
// variant (simple/MLP-4/NT/blit) shared while capping at 2.4-2.9 TB/s actual.
// Threads [0, memf4) copy memory; threads [memf4, totalf4) copy last_update.
// ---------------------------------------------------------------------------
__global__ __launch_bounds__(TPB) void copy1_kernel(const vfloat4* __restrict__ src,
                                                    vfloat4* __restrict__ dst,
                                                    const vfloat4* __restrict__ lu4,
                                                    vfloat4* __restrict__ outlu4,
                                                    unsigned memf4, unsigned totalf4) {
    unsigned gid = blockIdx.x * TPB + threadIdx.x;
    if (gid < memf4) {
        dst[gid] = src[gid];
    } else if (gid < totalf4) {
        outlu4[gid - memf4] = lu4[gid - memf4];
    }
}

// ---------------------------------------------------------------------------
// GRU kernel (runs AFTER the bulk copy): computes 8 batch rows per block and
// scatters winner rows + timestamps directly into the output. Dup
// suppression: shared-memory flag any thread may set (benign OR-race);
// NOTE: __ballot is per-wave (64 lanes) on CDNA — never use it for a
// 256-thread block reduction (R5's bug).
// ---------------------------------------------------------------------------
__global__ __launch_bounds__(TPB) void gru_kernel(
    const int*   __restrict__ ids,  const float* __restrict__ msg,
    const float* __restrict__ ts,   const float* __restrict__ mem,
    const float* __restrict__ b_ih, const float* __restrict__ b_hh,
    const float4* __restrict__ wt,
    float* __restrict__ out_mem,    float* __restrict__ out_lu,
    int B) {

    __shared__ float4 sxh[2][RPB][D4];   // [0]=x (messages), [1]=h (gathered memory)
    __shared__ int    s_id[RPB];
    __shared__ int    s_dup[RPB];

    const int tid  = threadIdx.x;
    const int base = blockIdx.x * RPB;

    if (tid < RPB) {
        s_id[tid]  = ids[base + tid];
        s_dup[tid] = 0;
    }
    __syncthreads();

    for (int it = tid; it < 2 * RPB * D4; it += TPB) {
        int which = it / (RPB * D4);
        int rem   = it - which * (RPB * D4);
        int r     = rem / D4;
        int k4    = rem - r * D4;
        const float* src = which ? (mem + (long)s_id[r] * D)
                                 : (msg + (long)(base + r) * D);
        ((float4*)sxh)[it] = *(const float4*)(src + 4 * k4);
    }
    // duplicate scan: row r loses if any later batch index has the same id
    for (int r = 0; r < RPB; ++r) {
        int my = s_id[r];
        for (int j = base + r + 1 + tid; j < B; j += TPB) {
            if (ids[j] == my) { s_dup[r] = 1; break; }
        }
    }
    __syncthreads();

    if (tid < D) {
        float acc[6][RPB];
        #pragma unroll
        for (int g = 0; g < 6; ++g)
            #pragma unroll
            for (int r = 0; r < RPB; ++r) acc[g][r] = 0.0f;

        const float4* wtB = wt + WT_HALF;
        for (int k4 = 0; k4 < D4; ++k4) {
            const int o = k4 * G3 + tid;
            float4 a0 = wt [o];
            float4 a1 = wt [o + D];
            float4 a2 = wt [o + 2 * D];
            float4 c0 = wtB[o];
            float4 c1 = wtB[o + D];
            float4 c2 = wtB[o + 2 * D];
            #pragma unroll
            for (int r = 0; r < RPB; ++r) {
                float4 xv = sxh[0][r][k4];
                float4 hv = sxh[1][r][k4];
                acc[0][r] += a0.x * xv.x + a0.y * xv.y + a0.z * xv.z + a0.w * xv.w;
                acc[1][r] += a1.x * xv.x + a1.y * xv.y + a1.z * xv.z + a1.w * xv.w;
                acc[2][r] += a2.x * xv.x + a2.y * xv.y + a2.z * xv.z + a2.w * xv.w;
                acc[3][r] += c0.x * hv.x + c0.y * hv.y + c0.z * hv.z + c0.w * hv.w;
                acc[4][r] += c1.x * hv.x + c1.y * hv.y + c1.z * hv.z + c1.w * hv.w;
                acc[5][r] += c2.x * hv.x + c2.y * hv.y + c2.z * hv.z + c2.w * hv.w;
            }
        }

        float bir = b_ih[tid], biz = b_ih[D + tid], bin_ = b_ih[2 * D + tid];
        float bhr = b_hh[tid], bhz = b_hh[D + tid], bhn  = b_hh[2 * D + tid];
        #pragma unroll
        for (int r = 0; r < RPB; ++r) {
            float i_r = acc[0][r] + bir;
            float i_z = acc[1][r] + biz;
            float i_n = acc[2][r] + bin_;
            float h_r = acc[3][r] + bhr;
            float h_z = acc[4][r] + bhz;
            float h_n = acc[5][r] + bhn;
            float rg = 1.0f / (1.0f + expf(-(i_r + h_r)));
            float zg = 1.0f / (1.0f + expf(-(i_z + h_z)));
            float ng = tanhf(i_n + rg * h_n);
            float hv = ((const float*)sxh[1][r])[tid];
            float outv = (1.0f - zg) * ng + zg * hv;
            if (!s_dup[r]) out_mem[(long)s_id[r] * D + tid] = outv;
        }
    }
    if (tid < RPB && !s_dup[tid]) out_lu[s_id[tid]] = ts[base + tid];
}

// ---------------- fallback GRU (uncoalesced weights, if ws too small) ------
__global__ __launch_bounds__(TPB) void gru_direct_kernel(
    const int*   __restrict__ ids,  const float* __restrict__ msg,
    const float* __restrict__ ts,   const float* __restrict__ mem,
    const float* __restrict__ w_ih, const float* __restrict__ w_hh,
    const float* __restrict__ b_ih, const float* __restrict__ b_hh,
    float* __restrict__ out_mem,    float* __restrict__ out_lu, int B) {
    int r = blockIdx.x;
    int tid = threadIdx.x;
    __shared__ float sx[D], sh[D];
    __shared__ int s_id, s_dup;
    if (tid == 0) { s_id = ids[r]; s_dup = 0; }
    __syncthreads();
    if (tid < D) { sx[tid] = msg[(long)r * D + tid]; sh[tid] = mem[(long)s_id * D + tid]; }
    for (int j = r + 1 + tid; j < B; j += TPB) if (ids[j] == s_id) { s_dup = 1; break; }
    __syncthreads();
    if (s_dup) return;
    if (tid < D) {
        float a[6] = {0,0,0,0,0,0};
        for (int k = 0; k < D; ++k) {
            float xv = sx[k], hv = sh[k];
            a[0] += w_ih[(long)(0*D+tid)*D+k] * xv;
            a[1] += w_ih[(long)(1*D+tid)*D+k] * xv;
            a[2] += w_ih[(long)(2*D+tid)*D+k] * xv;
            a[3] += w_hh[(long)(0*D+tid)*D+k] * hv;
            a[4] += w_hh[(long)(1*D+tid)*D+k] * hv;
            a[5] += w_hh[(long)(2*D+tid)*D+k] * hv;
        }
        float rg = 1.0f / (1.0f + expf(-(a[0] + b_ih[tid] + a[3] + b_hh[tid])));
        float zg = 1.0f / (1.0f + expf(-(a[1] + b_ih[D+tid] + a[4] + b_hh[D+tid])));
        float ng = tanhf(a[2] + b_ih[2*D+tid] + rg * (a[5] + b_hh[2*D+tid]));
        out_mem[(long)s_id * D + tid] = (1.0f - zg) * ng + zg * sh[tid];
    }
    if (tid == 0) out_lu[s_id] = ts[r];
}

extern "C" void kernel_launch(void* const* d_in, const int* in_sizes, int n_in,
                              void* d_out, int out_size, void* d_ws, size_t ws_size,
                              hipStream_t stream) {
    const int*   node_ids    = (const int*)d_in[0];
    const float* messages    = (const float*)d_in[1];
    const float* timestamps  = (const float*)d_in[2];
    const float* memory      = (const float*)d_in[3];
    const float* last_update = (const float*)d_in[4];
    const float* w_ih        = (const float*)d_in[5];
    const float* w_hh        = (const float*)d_in[6];
    const float* b_ih        = (const float*)d_in[7];
    const float* b_hh        = (const float*)d_in[8];
    float* out = (float*)d_out;

    const int B = in_sizes[0];          // 4096
    const int N = in_sizes[4];          // 500000
    const long memf = (long)N * D;      // 86,000,000 floats

    const unsigned memf4   = (unsigned)(memf / 4);   // 21,500,000
    const unsigned totalf4 = memf4 + (unsigned)(N / 4);  // +125,000
    const unsigned nblk    = (totalf4 + TPB - 1) / TPB;  // 84,473

    copy1_kernel<<<nblk, TPB, 0, stream>>>((const vfloat4*)memory,
                                           (vfloat4*)out,
                                           (const vfloat4*)last_update,
                                           (vfloat4*)(out + memf),
                                           memf4, totalf4);

    const size_t wt_bytes = (size_t)WT_F4 * sizeof(float4);
    if (ws_size >= wt_bytes) {
        float4* wt = (float4*)d_ws;
        prep_kernel<<<(WT_F4 + 255) / 256, 256, 0, stream>>>(w_ih, w_hh, wt);
        gru_kernel<<<B / RPB, TPB, 0, stream>>>(node_ids, messages, timestamps, memory,
                                                b_ih, b_hh, (const float4*)wt,
                                                out, out + memf, B);
    } else {
        gru_direct_kernel<<<B, TPB, 0, stream>>>(node_ids, messages, timestamps, memory,
                                                 w_ih, w_hh, b_ih, b_hh,
                                                 out, out + memf, B);
    }
}